// Round 12
// baseline (150.670 us; speedup 1.0000x reference)
//
#include <hip/hip_runtime.h>

// Problem constants (RefinementLayer1): B=2, L=192, D=768, NC=4, H=256
#define LSEQ 192
#define DIM  768
#define NCASE 4
#define HID  256
#define BATCH 2

// tanh(x) = 1 - 2/(exp2(K*x)+1), K = 2*log2(e). K folded into Bpack so the
// refine epilogue's tanh input (acc = K*mid) needs no extra scale.
#define TANH_K 2.885390081777927f

typedef float  floatx4 __attribute__((ext_vector_type(4)));
typedef __bf16 bf16x8  __attribute__((ext_vector_type(8)));
typedef __bf16 bf16x4  __attribute__((ext_vector_type(4)));

__device__ __forceinline__ float tanh_pre(float x) {   // x already * TANH_K
    float e = __builtin_amdgcn_exp2f(x);
    return 1.0f - 2.0f * __builtin_amdgcn_rcpf(e + 1.0f);
}

// tanh(u+v) = (tu+tv)/(1+tu*tv) from tu=tanh(u), tv=tanh(v): 1 trans + 3 ops.
__device__ __forceinline__ float tanh_add(float tu, float tv) {
    float den = __builtin_fmaf(tu, tv, 1.0f);
    return (tu + tv) * __builtin_amdgcn_rcpf(den);
}

// Workgroup barrier draining ONLY lgkmcnt (LDS); global prefetches stay in
// flight. 0xC07F = vmcnt(63) expcnt(7) lgkmcnt(0).
__device__ __forceinline__ void barrier_lds_only() {
    __builtin_amdgcn_sched_barrier(0);
    __builtin_amdgcn_s_waitcnt(0xC07F);
    __builtin_amdgcn_s_barrier();
    __builtin_amdgcn_sched_barrier(0);
}

template <int CTRL>
__device__ __forceinline__ float dpp_add(float v) {
    int x = __builtin_amdgcn_update_dpp(0, __builtin_bit_cast(int, v),
                                        CTRL, 0xF, 0xF, true);
    return v + __builtin_bit_cast(float, x);
}
__device__ __forceinline__ float row16_reduce(float v) {
    v = dpp_add<0xB1>(v);    // quad_perm xor1
    v = dpp_add<0x4E>(v);    // quad_perm xor2
    v = dpp_add<0x141>(v);   // row_half_mirror
    v = dpp_add<0x140>(v);   // row_mirror
    return v;
}

// ---------------------------------------------------------------------------
// MFMA fragment layouts (m89/m91-verified, 16x16x32 bf16):
//   A: lane holds A[m = lane&15][k = (lane>>4)*8 + j]   (bf16x8)
//   B: lane holds B[k = (lane>>4)*8 + j][h = lane&15]   (bf16x8)
//   C/D: lane reg holds D[row = (lane>>4)*4 + reg][col = lane&15]
// ---------------------------------------------------------------------------

// ---------------------------------------------------------------------------
// Kernel 1 "prep": two jobs by blockIdx.
//  blocks [0,1920): lin unit (rt = blk/80, cg = blk%80): 16 rows x 16 cols,
//    lin = TANH(seq @ [Wp|Wa] + bias) (pre-activated for refine's tanh
//    addition formula). 4-WAY SPLIT-K: wave w covers k in [w*192, w*192+192)
//    as 6 chunks (R11's single-wave 24-chunk serial chain at 2.4 waves/SIMD
//    was latency-bound and ~half of total wall time); fp32 LDS combine,
//    wave 0 applies bias+tanh and stores. bf16 hi/lo in-register, hh+lh+hl.
//  blocks [1920,2064): pack Wmid/bmid -> Bpack bf16 B-frags, scaled by
//    TANH_K (k rows 256..259 = bs rows, k=260 = bmid row, k>260 zero).
// ---------------------------------------------------------------------------
__global__ __launch_bounds__(256) void prep(
    const float* __restrict__ seq, const float* __restrict__ Wp,
    const float* __restrict__ Wa,  const float* __restrict__ bp,
    const float* __restrict__ ba,  const float* __restrict__ Wmid,
    const float* __restrict__ bmid,
    float* __restrict__ lin, bf16x8* __restrict__ Bpack)
{
    const int blk = blockIdx.x;
    const int tid = threadIdx.x;

    if (blk >= 1920) {                     // ---- pack job
        int u = (blk - 1920) * 256 + tid;  // 0..36863 (one bf16x8 each)
        int lane = u & 63, f = u >> 6;
        int ct = f & 15, nk = f >> 4;      // nk = n*9 + kc
        int kc = nk % 9, n = nk / 9;
        int h = ct * 16 + (lane & 15);
        int kbase = kc * 32 + ((lane >> 4) & 3) * 8;
        bf16x8 v;
        #pragma unroll
        for (int j = 0; j < 8; j++) {
            int k = kbase + j;
            float x;
            if (k < 260)       x = Wmid[(size_t)(n * 260 + k) * 256 + h];
            else if (k == 260) x = bmid[n * 256 + h];
            else               x = 0.0f;
            v[j] = (__bf16)(TANH_K * x);
        }
        Bpack[u] = v;
        return;
    }

    // ---- lin unit: rt = blk/80, cg = blk%80; wave w = K-quarter
    const int w = tid >> 6, lane = tid & 63;
    const int rt = blk / 80, cg = blk % 80;
    const int quad  = lane >> 4;
    const int col16 = lane & 15;

    __shared__ float cmb[3][256];          // waves 1..3 partials, 3 KB

    const int arow = rt * 16 + col16;          // A: m = lane&15
    const int col  = cg * 16 + col16;          // output col 0..1279
    const int kofs = w * 192;
    const float* aptr = seq + (size_t)arow * DIM + kofs + quad * 8;
    const float* wbase = (cg < 16) ? (Wp + col) : (Wa + (col - 256));
    const int    wstr  = (cg < 16) ? HID : (NCASE * HID);

    floatx4 acc = {};
    floatx4 a0 = *(const floatx4*)(aptr);
    floatx4 a1 = *(const floatx4*)(aptr + 4);
    float bv[8];
    #pragma unroll
    for (int j = 0; j < 8; j++)
        bv[j] = wbase[(size_t)(kofs + quad * 8 + j) * wstr];

    #pragma unroll
    for (int kc = 0; kc < 6; kc++) {
        bf16x8 ah, al, bh, bl;
        #pragma unroll
        for (int j = 0; j < 4; j++) {
            __bf16 h0 = (__bf16)a0[j];
            ah[j] = h0; al[j] = (__bf16)(a0[j] - (float)h0);
            __bf16 h1 = (__bf16)a1[j];
            ah[4 + j] = h1; al[4 + j] = (__bf16)(a1[j] - (float)h1);
        }
        #pragma unroll
        for (int j = 0; j < 8; j++) {
            __bf16 h = (__bf16)bv[j];
            bh[j] = h; bl[j] = (__bf16)(bv[j] - (float)h);
        }
        if (kc < 5) {                      // prefetch next chunk
            a0 = *(const floatx4*)(aptr + (kc + 1) * 32);
            a1 = *(const floatx4*)(aptr + (kc + 1) * 32 + 4);
            #pragma unroll
            for (int j = 0; j < 8; j++)
                bv[j] = wbase[(size_t)(kofs + (kc + 1) * 32 + quad * 8 + j) * wstr];
        }
        acc = __builtin_amdgcn_mfma_f32_16x16x32_bf16(ah, bh, acc, 0, 0, 0);
        acc = __builtin_amdgcn_mfma_f32_16x16x32_bf16(al, bh, acc, 0, 0, 0);
        acc = __builtin_amdgcn_mfma_f32_16x16x32_bf16(ah, bl, acc, 0, 0, 0);
    }

    if (w > 0) *(floatx4*)&cmb[w - 1][lane * 4] = acc;
    __syncthreads();
    if (w == 0) {
        #pragma unroll
        for (int i = 0; i < 3; i++) {
            floatx4 p = *(const floatx4*)&cmb[i][lane * 4];
            acc += p;
        }
        const float bias = (cg < 16) ? bp[col] : ba[col - 256];
        #pragma unroll
        for (int reg = 0; reg < 4; reg++)
            lin[(size_t)(rt * 16 + quad * 4 + reg) * 1280 + col] =
                tanh_pre(TANH_K * (acc[reg] + bias));     // pre-activated
    }
}

// ---------------------------------------------------------------------------
// Kernel 2: fused main — UNCHANGED from R11 (74.5 us measured). 512 threads /
// 8 waves; wave owns 2 ct-frags; tile = 64 rows (8p x 8a) x 256 cols, fixed
// (b,n). A SHARED via LDS (each thread tanh_add-generates a half slot);
// B-frags global->regs, non-redundant. lgkm-only barriers keep prefetches in
// flight. K: 8 tanh chunks + folded bs/bmid chunk. Epilogue: tanh(acc).Wout,
// DPP reduce, 8-way cross-wave LDS combine, store.
// ---------------------------------------------------------------------------
__global__ __launch_bounds__(512, 4) void refine_main(
    const float* __restrict__ lin,        // [384][1280], PRE-TANH'd
    const float* __restrict__ base_score, // [B][L][NC][L]
    const float* __restrict__ Wout,       // [NC][256]
    const bf16x8* __restrict__ Bpack,     // packed Wmid frags (K-scaled)
    float* __restrict__ out)              // [B][L][NC][L]
{
    const int bx = blockIdx.x;            // 576 = 24*24
    const int n  = blockIdx.y;
    const int b  = blockIdx.z;
    const int ptile = bx / 24, atile = bx % 24;
    const int p0 = ptile * 8, a0r = atile * 8;

    const int tid   = threadIdx.x;
    const int w     = tid >> 6;           // wave 0..7, owns ct = w*2, w*2+1
    const int lane  = tid & 63;
    const int quad  = lane >> 4;
    const int col16 = lane & 15;

    __shared__ __align__(16) __bf16 A0[256 * 8];   // 4 KB frag buf (even kc)
    __shared__ __align__(16) __bf16 A1[256 * 8];   // 4 KB frag buf (odd kc)
    __shared__ float red[8][64];

    // A-gen half-slot: slot s = tid>>1 (l = s&63), half = tid&1.
    const int s_g    = tid >> 1;
    const int h2     = tid & 1;
    const int l_g    = s_g & 63;
    const int m_gen  = ((s_g >> 6) << 4) + (l_g & 15);
    const int kq     = (l_g >> 4) * 8 + h2 * 4;
    const int quad_g = l_g >> 4;

    const int pg = p0 + (m_gen >> 3), ag = a0r + (m_gen & 7);
    const float* hp_ptr = lin + (size_t)(b * LSEQ + pg) * 1280 + kq;
    const float* ha_ptr = lin + (size_t)(b * LSEQ + ag) * 1280 + 256 + n * 256 + kq;

    // B frags for wave w: index ((n*9 + kc)*16 + w*2 + ct)*64 + lane
    const bf16x8* bbase = Bpack + ((size_t)(n * 9) * 16 + w * 2) * 64 + lane;

    // ---- prologue
    float bs4[4] = {};
    if (quad_g == 0 && h2 == 0) {
        #pragma unroll
        for (int j = 0; j < 4; j++)
            bs4[j] = base_score[((size_t)(b * LSEQ + pg) * NCASE + j) * LSEQ + ag];
    }
    float wo[2];
    #pragma unroll
    for (int ct = 0; ct < 2; ct++)
        wo[ct] = Wout[n * 256 + w * 32 + ct * 16 + col16];

    bf16x8 bcur[2];
    #pragma unroll
    for (int ct = 0; ct < 2; ct++) bcur[ct] = bbase[ct * 64];

    floatx4 hp = *(const floatx4*)(hp_ptr);
    floatx4 ha = *(const floatx4*)(ha_ptr);
    {   // av(0) -> A0 (half-slot)
        bf16x4 av;
        #pragma unroll
        for (int j = 0; j < 4; j++) av[j] = (__bf16)tanh_add(hp[j], ha[j]);
        *(bf16x4*)&A0[tid * 4] = av;
    }
    hp = *(const floatx4*)(hp_ptr + 32);   // chunk 1 inputs
    ha = *(const floatx4*)(ha_ptr + 32);
    barrier_lds_only();

    floatx4 acc[4][2] = {};   // [rt][ct]

    #pragma unroll
    for (int kc = 0; kc < 9; kc++) {
        // B prefetch for chunk kc+1 (stays in flight across the barrier)
        bf16x8 bnext[2];
        if (kc < 8) {
            #pragma unroll
            for (int ct = 0; ct < 2; ct++)
                bnext[ct] = bbase[((kc + 1) * 16 + ct) * 64];
        }
        // generate av(kc+1) into the other buffer (overlaps MFMA below)
        if (kc < 7) {
            floatx4 u0 = hp, v0 = ha;
            if (kc < 6) {                 // prefetch inputs for chunk kc+2
                hp = *(const floatx4*)(hp_ptr + (kc + 2) * 32);
                ha = *(const floatx4*)(ha_ptr + (kc + 2) * 32);
            }
            bf16x4 av;
            #pragma unroll
            for (int j = 0; j < 4; j++) av[j] = (__bf16)tanh_add(u0[j], v0[j]);
            __bf16* buf = ((kc + 1) & 1) ? A1 : A0;
            *(bf16x4*)&buf[tid * 4] = av;
        } else if (kc == 7) {             // folded chunk: A = [bs(4), 1, 0...]
            bf16x4 av = {};
            if (quad_g == 0) {
                if (h2 == 0) {
                    #pragma unroll
                    for (int j = 0; j < 4; j++) av[j] = (__bf16)bs4[j];
                } else {
                    av[0] = (__bf16)1.0f;  // k = 4 pairs with bmid row
                }
            }
            *(bf16x4*)&A0[tid * 4] = av;   // (7+1)&1 == 0
        }

        // MFMA(kc) from buf[kc&1]
        const __bf16* rb = (kc & 1) ? A1 : A0;
        bf16x8 af[4];
        #pragma unroll
        for (int rt = 0; rt < 4; rt++)
            af[rt] = *(const bf16x8*)&rb[(rt * 64 + lane) * 8];
        #pragma unroll
        for (int rt = 0; rt < 4; rt++)
            #pragma unroll
            for (int ct = 0; ct < 2; ct++)
                acc[rt][ct] = __builtin_amdgcn_mfma_f32_16x16x32_bf16(
                    af[rt], bcur[ct], acc[rt][ct], 0, 0, 0);
        #pragma unroll
        for (int ct = 0; ct < 2; ct++) bcur[ct] = bnext[ct];
        if (kc < 8) barrier_lds_only();
    }

    // ---- epilogue: tanh(acc) . Wout (acc = K*mid), DPP reduce, combine
    #pragma unroll
    for (int rt = 0; rt < 4; rt++) {
        #pragma unroll
        for (int reg = 0; reg < 4; reg++) {
            float rs = tanh_pre(acc[rt][0][reg]) * wo[0]
                     + tanh_pre(acc[rt][1][reg]) * wo[1];
            rs = row16_reduce(rs);
            if (col16 == 0) red[w][rt * 16 + quad * 4 + reg] = rs;
        }
    }
    barrier_lds_only();

    if (tid < 64) {
        float total = red[0][tid] + red[1][tid] + red[2][tid] + red[3][tid]
                    + red[4][tid] + red[5][tid] + red[6][tid] + red[7][tid];
        const int p = p0 + (tid >> 3), a = a0r + (tid & 7);
        out[((size_t)(b * LSEQ + p) * NCASE + n) * LSEQ + a] = total;
    }
}

// ---------------------------------------------------------------------------
extern "C" void kernel_launch(void* const* d_in, const int* in_sizes, int n_in,
                              void* d_out, int out_size, void* d_ws, size_t ws_size,
                              hipStream_t stream) {
    const float* seq  = (const float*)d_in[0];
    const float* bsc  = (const float*)d_in[1];
    const float* Wp   = (const float*)d_in[2];
    const float* bp   = (const float*)d_in[3];
    const float* Wa   = (const float*)d_in[4];
    const float* ba   = (const float*)d_in[5];
    const float* Wmid = (const float*)d_in[6];
    const float* bmid = (const float*)d_in[7];
    const float* Wout = (const float*)d_in[8];
    float* out = (float*)d_out;

    char* ws = (char*)d_ws;
    float*  lin   = (float*)(ws);                      // 1,966,080 B
    bf16x8* Bpack = (bf16x8*)(ws + 1966080);           //   589,824 B

    prep<<<2064, 256, 0, stream>>>(seq, Wp, Wa, bp, ba, Wmid, bmid, lin, Bpack);
    refine_main<<<dim3(576, NCASE, BATCH), 512, 0, stream>>>(
        lin, bsc, Wout, Bpack, out);
}

// Round 13
// 148.412 us; speedup vs baseline: 1.0152x; 1.0152x over previous
//
#include <hip/hip_runtime.h>

// Problem constants (RefinementLayer1): B=2, L=192, D=768, NC=4, H=256
#define LSEQ 192
#define DIM  768
#define NCASE 4
#define HID  256
#define BATCH 2

// tanh(x) = 1 - 2/(exp2(K*x)+1), K = 2*log2(e). K folded into Bpack so the
// refine epilogue's tanh input (acc = K*mid) needs no extra scale.
#define TANH_K 2.885390081777927f

typedef float  floatx4 __attribute__((ext_vector_type(4)));
typedef __bf16 bf16x8  __attribute__((ext_vector_type(8)));
typedef __bf16 bf16x4  __attribute__((ext_vector_type(4)));

__device__ __forceinline__ float tanh_pre(float x) {   // x already * TANH_K
    float e = __builtin_amdgcn_exp2f(x);
    return 1.0f - 2.0f * __builtin_amdgcn_rcpf(e + 1.0f);
}

// tanh(u+v) = (tu+tv)/(1+tu*tv) from tu=tanh(u), tv=tanh(v): 1 trans + 3 ops.
__device__ __forceinline__ float tanh_add(float tu, float tv) {
    float den = __builtin_fmaf(tu, tv, 1.0f);
    return (tu + tv) * __builtin_amdgcn_rcpf(den);
}

// Workgroup barrier draining ONLY lgkmcnt (LDS); global prefetches stay in
// flight. 0xC07F = vmcnt(63) expcnt(7) lgkmcnt(0).
__device__ __forceinline__ void barrier_lds_only() {
    __builtin_amdgcn_sched_barrier(0);
    __builtin_amdgcn_s_waitcnt(0xC07F);
    __builtin_amdgcn_s_barrier();
    __builtin_amdgcn_sched_barrier(0);
}

template <int CTRL>
__device__ __forceinline__ float dpp_add(float v) {
    int x = __builtin_amdgcn_update_dpp(0, __builtin_bit_cast(int, v),
                                        CTRL, 0xF, 0xF, true);
    return v + __builtin_bit_cast(float, x);
}
__device__ __forceinline__ float row16_reduce(float v) {
    v = dpp_add<0xB1>(v);    // quad_perm xor1
    v = dpp_add<0x4E>(v);    // quad_perm xor2
    v = dpp_add<0x141>(v);   // row_half_mirror
    v = dpp_add<0x140>(v);   // row_mirror
    return v;
}

// ---------------------------------------------------------------------------
// MFMA fragment layouts (m89/m91-verified, 16x16x32 bf16):
//   A: lane holds A[m = lane&15][k = (lane>>4)*8 + j]   (bf16x8)
//   B: lane holds B[k = (lane>>4)*8 + j][h = lane&15]   (bf16x8)
//   C/D: lane reg holds D[row = (lane>>4)*4 + reg][col = lane&15]
// ---------------------------------------------------------------------------

// ---------------------------------------------------------------------------
// Kernel 1 "prep" (unchanged from R12 — prep is NOT the bottleneck; R12's 4x
// parallelization moved total by +0.1 us, proving the residual gap is
// harness-fixed overhead):
//  blocks [0,1920): lin unit: 16 rows x 16 cols, lin = TANH(seq@[Wp|Wa]+bias)
//    (pre-activated), 4-way split-K, fp32 LDS combine, bf16 hi/lo MFMA.
//  blocks [1920,2064): pack Wmid/bmid -> Bpack bf16 B-frags (TANH_K folded).
// ---------------------------------------------------------------------------
__global__ __launch_bounds__(256) void prep(
    const float* __restrict__ seq, const float* __restrict__ Wp,
    const float* __restrict__ Wa,  const float* __restrict__ bp,
    const float* __restrict__ ba,  const float* __restrict__ Wmid,
    const float* __restrict__ bmid,
    float* __restrict__ lin, bf16x8* __restrict__ Bpack)
{
    const int blk = blockIdx.x;
    const int tid = threadIdx.x;

    if (blk >= 1920) {                     // ---- pack job
        int u = (blk - 1920) * 256 + tid;  // 0..36863 (one bf16x8 each)
        int lane = u & 63, f = u >> 6;
        int ct = f & 15, nk = f >> 4;      // nk = n*9 + kc
        int kc = nk % 9, n = nk / 9;
        int h = ct * 16 + (lane & 15);
        int kbase = kc * 32 + ((lane >> 4) & 3) * 8;
        bf16x8 v;
        #pragma unroll
        for (int j = 0; j < 8; j++) {
            int k = kbase + j;
            float x;
            if (k < 260)       x = Wmid[(size_t)(n * 260 + k) * 256 + h];
            else if (k == 260) x = bmid[n * 256 + h];
            else               x = 0.0f;
            v[j] = (__bf16)(TANH_K * x);
        }
        Bpack[u] = v;
        return;
    }

    // ---- lin unit: rt = blk/80, cg = blk%80; wave w = K-quarter
    const int w = tid >> 6, lane = tid & 63;
    const int rt = blk / 80, cg = blk % 80;
    const int quad  = lane >> 4;
    const int col16 = lane & 15;

    __shared__ float cmb[3][256];          // waves 1..3 partials, 3 KB

    const int arow = rt * 16 + col16;          // A: m = lane&15
    const int col  = cg * 16 + col16;          // output col 0..1279
    const int kofs = w * 192;
    const float* aptr = seq + (size_t)arow * DIM + kofs + quad * 8;
    const float* wbase = (cg < 16) ? (Wp + col) : (Wa + (col - 256));
    const int    wstr  = (cg < 16) ? HID : (NCASE * HID);

    floatx4 acc = {};
    floatx4 a0 = *(const floatx4*)(aptr);
    floatx4 a1 = *(const floatx4*)(aptr + 4);
    float bv[8];
    #pragma unroll
    for (int j = 0; j < 8; j++)
        bv[j] = wbase[(size_t)(kofs + quad * 8 + j) * wstr];

    #pragma unroll
    for (int kc = 0; kc < 6; kc++) {
        bf16x8 ah, al, bh, bl;
        #pragma unroll
        for (int j = 0; j < 4; j++) {
            __bf16 h0 = (__bf16)a0[j];
            ah[j] = h0; al[j] = (__bf16)(a0[j] - (float)h0);
            __bf16 h1 = (__bf16)a1[j];
            ah[4 + j] = h1; al[4 + j] = (__bf16)(a1[j] - (float)h1);
        }
        #pragma unroll
        for (int j = 0; j < 8; j++) {
            __bf16 h = (__bf16)bv[j];
            bh[j] = h; bl[j] = (__bf16)(bv[j] - (float)h);
        }
        if (kc < 5) {                      // prefetch next chunk
            a0 = *(const floatx4*)(aptr + (kc + 1) * 32);
            a1 = *(const floatx4*)(aptr + (kc + 1) * 32 + 4);
            #pragma unroll
            for (int j = 0; j < 8; j++)
                bv[j] = wbase[(size_t)(kofs + (kc + 1) * 32 + quad * 8 + j) * wstr];
        }
        acc = __builtin_amdgcn_mfma_f32_16x16x32_bf16(ah, bh, acc, 0, 0, 0);
        acc = __builtin_amdgcn_mfma_f32_16x16x32_bf16(al, bh, acc, 0, 0, 0);
        acc = __builtin_amdgcn_mfma_f32_16x16x32_bf16(ah, bl, acc, 0, 0, 0);
    }

    if (w > 0) *(floatx4*)&cmb[w - 1][lane * 4] = acc;
    __syncthreads();
    if (w == 0) {
        #pragma unroll
        for (int i = 0; i < 3; i++) {
            floatx4 p = *(const floatx4*)&cmb[i][lane * 4];
            acc += p;
        }
        const float bias = (cg < 16) ? bp[col] : ba[col - 256];
        #pragma unroll
        for (int reg = 0; reg < 4; reg++)
            lin[(size_t)(rt * 16 + quad * 4 + reg) * 1280 + col] =
                tanh_pre(TANH_K * (acc[reg] + bias));     // pre-activated
    }
}

// ---------------------------------------------------------------------------
// Kernel 2: fused main — R12 structure with ONE change: __launch_bounds__
// (512, 6) -> 3 blocks/CU (24 waves/CU) instead of 2. R12 showed VALU (the
// longest pipe, 37 us busy) at only 50% utilization with 9 lockstep barriers
// per tile and 38% occupancy; +50% resident waves from OTHER blocks (whose
// barrier phases are unaligned) should fill the stall windows. Regs: 80
// unified <= 85 budget for 6 waves/SIMD — no spill expected.
// ---------------------------------------------------------------------------
__global__ __launch_bounds__(512, 6) void refine_main(
    const float* __restrict__ lin,        // [384][1280], PRE-TANH'd
    const float* __restrict__ base_score, // [B][L][NC][L]
    const float* __restrict__ Wout,       // [NC][256]
    const bf16x8* __restrict__ Bpack,     // packed Wmid frags (K-scaled)
    float* __restrict__ out)              // [B][L][NC][L]
{
    const int bx = blockIdx.x;            // 576 = 24*24
    const int n  = blockIdx.y;
    const int b  = blockIdx.z;
    const int ptile = bx / 24, atile = bx % 24;
    const int p0 = ptile * 8, a0r = atile * 8;

    const int tid   = threadIdx.x;
    const int w     = tid >> 6;           // wave 0..7, owns ct = w*2, w*2+1
    const int lane  = tid & 63;
    const int quad  = lane >> 4;
    const int col16 = lane & 15;

    __shared__ __align__(16) __bf16 A0[256 * 8];   // 4 KB frag buf (even kc)
    __shared__ __align__(16) __bf16 A1[256 * 8];   // 4 KB frag buf (odd kc)
    __shared__ float red[8][64];

    // A-gen half-slot: slot s = tid>>1 (l = s&63), half = tid&1.
    const int s_g    = tid >> 1;
    const int h2     = tid & 1;
    const int l_g    = s_g & 63;
    const int m_gen  = ((s_g >> 6) << 4) + (l_g & 15);
    const int kq     = (l_g >> 4) * 8 + h2 * 4;
    const int quad_g = l_g >> 4;

    const int pg = p0 + (m_gen >> 3), ag = a0r + (m_gen & 7);
    const float* hp_ptr = lin + (size_t)(b * LSEQ + pg) * 1280 + kq;
    const float* ha_ptr = lin + (size_t)(b * LSEQ + ag) * 1280 + 256 + n * 256 + kq;

    // B frags for wave w: index ((n*9 + kc)*16 + w*2 + ct)*64 + lane
    const bf16x8* bbase = Bpack + ((size_t)(n * 9) * 16 + w * 2) * 64 + lane;

    // ---- prologue
    float bs4[4] = {};
    if (quad_g == 0 && h2 == 0) {
        #pragma unroll
        for (int j = 0; j < 4; j++)
            bs4[j] = base_score[((size_t)(b * LSEQ + pg) * NCASE + j) * LSEQ + ag];
    }
    float wo[2];
    #pragma unroll
    for (int ct = 0; ct < 2; ct++)
        wo[ct] = Wout[n * 256 + w * 32 + ct * 16 + col16];

    bf16x8 bcur[2];
    #pragma unroll
    for (int ct = 0; ct < 2; ct++) bcur[ct] = bbase[ct * 64];

    floatx4 hp = *(const floatx4*)(hp_ptr);
    floatx4 ha = *(const floatx4*)(ha_ptr);
    {   // av(0) -> A0 (half-slot)
        bf16x4 av;
        #pragma unroll
        for (int j = 0; j < 4; j++) av[j] = (__bf16)tanh_add(hp[j], ha[j]);
        *(bf16x4*)&A0[tid * 4] = av;
    }
    hp = *(const floatx4*)(hp_ptr + 32);   // chunk 1 inputs
    ha = *(const floatx4*)(ha_ptr + 32);
    barrier_lds_only();

    floatx4 acc[4][2] = {};   // [rt][ct]

    #pragma unroll
    for (int kc = 0; kc < 9; kc++) {
        // B prefetch for chunk kc+1 (stays in flight across the barrier)
        bf16x8 bnext[2];
        if (kc < 8) {
            #pragma unroll
            for (int ct = 0; ct < 2; ct++)
                bnext[ct] = bbase[((kc + 1) * 16 + ct) * 64];
        }
        // generate av(kc+1) into the other buffer (overlaps MFMA below)
        if (kc < 7) {
            floatx4 u0 = hp, v0 = ha;
            if (kc < 6) {                 // prefetch inputs for chunk kc+2
                hp = *(const floatx4*)(hp_ptr + (kc + 2) * 32);
                ha = *(const floatx4*)(ha_ptr + (kc + 2) * 32);
            }
            bf16x4 av;
            #pragma unroll
            for (int j = 0; j < 4; j++) av[j] = (__bf16)tanh_add(u0[j], v0[j]);
            __bf16* buf = ((kc + 1) & 1) ? A1 : A0;
            *(bf16x4*)&buf[tid * 4] = av;
        } else if (kc == 7) {             // folded chunk: A = [bs(4), 1, 0...]
            bf16x4 av = {};
            if (quad_g == 0) {
                if (h2 == 0) {
                    #pragma unroll
                    for (int j = 0; j < 4; j++) av[j] = (__bf16)bs4[j];
                } else {
                    av[0] = (__bf16)1.0f;  // k = 4 pairs with bmid row
                }
            }
            *(bf16x4*)&A0[tid * 4] = av;   // (7+1)&1 == 0
        }

        // MFMA(kc) from buf[kc&1]
        const __bf16* rb = (kc & 1) ? A1 : A0;
        bf16x8 af[4];
        #pragma unroll
        for (int rt = 0; rt < 4; rt++)
            af[rt] = *(const bf16x8*)&rb[(rt * 64 + lane) * 8];
        #pragma unroll
        for (int rt = 0; rt < 4; rt++)
            #pragma unroll
            for (int ct = 0; ct < 2; ct++)
                acc[rt][ct] = __builtin_amdgcn_mfma_f32_16x16x32_bf16(
                    af[rt], bcur[ct], acc[rt][ct], 0, 0, 0);
        #pragma unroll
        for (int ct = 0; ct < 2; ct++) bcur[ct] = bnext[ct];
        if (kc < 8) barrier_lds_only();
    }

    // ---- epilogue: tanh(acc) . Wout (acc = K*mid), DPP reduce, combine
    #pragma unroll
    for (int rt = 0; rt < 4; rt++) {
        #pragma unroll
        for (int reg = 0; reg < 4; reg++) {
            float rs = tanh_pre(acc[rt][0][reg]) * wo[0]
                     + tanh_pre(acc[rt][1][reg]) * wo[1];
            rs = row16_reduce(rs);
            if (col16 == 0) red[w][rt * 16 + quad * 4 + reg] = rs;
        }
    }
    barrier_lds_only();

    if (tid < 64) {
        float total = red[0][tid] + red[1][tid] + red[2][tid] + red[3][tid]
                    + red[4][tid] + red[5][tid] + red[6][tid] + red[7][tid];
        const int p = p0 + (tid >> 3), a = a0r + (tid & 7);
        out[((size_t)(b * LSEQ + p) * NCASE + n) * LSEQ + a] = total;
    }
}

// ---------------------------------------------------------------------------
extern "C" void kernel_launch(void* const* d_in, const int* in_sizes, int n_in,
                              void* d_out, int out_size, void* d_ws, size_t ws_size,
                              hipStream_t stream) {
    const float* seq  = (const float*)d_in[0];
    const float* bsc  = (const float*)d_in[1];
    const float* Wp   = (const float*)d_in[2];
    const float* bp   = (const float*)d_in[3];
    const float* Wa   = (const float*)d_in[4];
    const float* ba   = (const float*)d_in[5];
    const float* Wmid = (const float*)d_in[6];
    const float* bmid = (const float*)d_in[7];
    const float* Wout = (const float*)d_in[8];
    float* out = (float*)d_out;

    char* ws = (char*)d_ws;
    float*  lin   = (float*)(ws);                      // 1,966,080 B
    bf16x8* Bpack = (bf16x8*)(ws + 1966080);           //   589,824 B

    prep<<<2064, 256, 0, stream>>>(seq, Wp, Wa, bp, ba, Wmid, bmid, lin, Bpack);
    refine_main<<<dim3(576, NCASE, BATCH), 512, 0, stream>>>(
        lin, bsc, Wout, Bpack, out);
}